// Round 1
// baseline (326.279 us; speedup 1.0000x reference)
//
#include <hip/hip_runtime.h>
#include <hip/hip_fp16.h>

// GCN 2-layer GraphConv (norm='both'), fp32 in/out, fp16 intermediates.
// Round 7: binned CSR build (counting sort by dst>>8) replaces the
//          random-scatter rank/place pipeline:
//   k1:  hist_s atomics + LDS bin-histogram (shadowed under xw1)
//   scan_bins: 391-entry scan (1 block)  [replaces 3-kernel 100K scan]
//   kB:  multisplit scatter of packed (dstoff,src) into per-bin regions
//   kC:  per-bin local CSR build -> col/rowptr/deg/in_norm (block-local scatter)
// Pull kernels unchanged.
//
// ws(int): hist_s[N] | deg[N] | rowptr[N] | bin_cnt[512] | bin_base[516] |
//          gcur[512] | binbuf[E] | col[E]
// ws(f32): in_norm[N]
// ws(f16): h1[64N] | h2[32N]

#define BIN_SH 8              // 256 nodes per bin
#define NBINS_PAD 512
#define KB_EPT 16             // edges per thread in kB (4096 per block)

// ---- K1: hist_s atomics + LDS bin-hist (even blocks) || h1 = x @ W1 (odd) ----
__global__ __launch_bounds__(256) void k1_hist_xw1(
    const int* __restrict__ src, const int* __restrict__ dst,
    int* __restrict__ hist_s, int* __restrict__ bin_cnt,
    const float* __restrict__ x, const float* __restrict__ W,
    __half* __restrict__ h1, int E, int n, int HB, int GX, int EPB, int nbins) {
  __shared__ float Ws[64 * 64];
  __shared__ float xs[16 * 64];
  __shared__ int lcnt[NBINS_PAD];
  int bid = blockIdx.x;
  int Mn = (HB < GX) ? HB : GX;
  bool isHist;
  int idx;
  if (bid < 2 * Mn) { isHist = !(bid & 1); idx = bid >> 1; }
  else               { isHist = (HB > GX); idx = bid - 2 * Mn + Mn; }

  int t = threadIdx.x;
  if (isHist) {
    for (int i = t; i < NBINS_PAD; i += 256) lcnt[i] = 0;
    __syncthreads();
    int e0 = idx * EPB;
    int e1 = e0 + EPB; if (e1 > E) e1 = E;
    for (int e = e0 + t; e < e1; e += 256) {
      atomicAdd(&hist_s[src[e]], 1);          // fire-and-forget, pipelined
      atomicAdd(&lcnt[dst[e] >> BIN_SH], 1);  // LDS
    }
    __syncthreads();
    for (int i = t; i < nbins; i += 256)
      if (lcnt[i]) atomicAdd(&bin_cnt[i], lcnt[i]);
    return;
  }
#pragma unroll
  for (int i = 0; i < 16; i++) Ws[i * 256 + t] = W[i * 256 + t];
  int row0 = idx * 16;
#pragma unroll
  for (int i = 0; i < 4; i++) {
    int gi = i * 256 + t;
    int r = gi >> 6, k = gi & 63;
    int row = row0 + r;
    xs[gi] = (row < n) ? x[row * 64 + k] : 0.0f;
  }
  __syncthreads();
  int c = t & 63, rq = t >> 6;
  float acc[4] = {0.f, 0.f, 0.f, 0.f};
#pragma unroll 16
  for (int k = 0; k < 64; k++) {
    float w = Ws[k * 64 + c];
#pragma unroll
    for (int rr = 0; rr < 4; rr++) acc[rr] += xs[(rq + rr * 4) * 64 + k] * w;
  }
#pragma unroll
  for (int rr = 0; rr < 4; rr++) {
    int row = row0 + rq + rr * 4;
    if (row < n) h1[(size_t)row * 64 + c] = __float2half(acc[rr]);
  }
}

// ---- scan of bin_cnt -> bin_base (exclusive) + total; init gcur ----
__global__ __launch_bounds__(512) void scan_bins(const int* __restrict__ bin_cnt,
                                                 int* __restrict__ bin_base,
                                                 int* __restrict__ gcur, int nbins) {
  __shared__ int tmp[512];
  int t = threadIdx.x;
  int v = (t < nbins) ? bin_cnt[t] : 0;
  tmp[t] = v;
  __syncthreads();
#pragma unroll
  for (int off = 1; off < 512; off <<= 1) {
    int val = (t >= off) ? tmp[t - off] : 0;
    __syncthreads();
    tmp[t] += val;
    __syncthreads();
  }
  int ex = tmp[t] - v;
  if (t < nbins) { bin_base[t] = ex; gcur[t] = ex; }
  if (t == 511) bin_base[nbins] = tmp[511];
}

// ---- kB: multisplit scatter into per-bin regions ----
// entry = (dst&255)<<17 | src  (src < 2^17)
__global__ __launch_bounds__(256) void kB_binscatter(
    const int* __restrict__ src, const int* __restrict__ dst,
    int* __restrict__ gcur, int* __restrict__ binbuf, int E, int nbins) {
  __shared__ int lcnt[NBINS_PAD];
  __shared__ int lbase[NBINS_PAD];
  int t = threadIdx.x;
  for (int i = t; i < NBINS_PAD; i += 256) lcnt[i] = 0;
  __syncthreads();
  int base = blockIdx.x * (256 * KB_EPT);
  int mybin[KB_EPT], myrank[KB_EPT], myval[KB_EPT];
#pragma unroll
  for (int i = 0; i < KB_EPT; i++) {
    int e = base + i * 256 + t;
    if (e < E) {
      int d = dst[e];
      int s = src[e];
      int b = d >> BIN_SH;
      mybin[i] = b;
      myval[i] = ((d & ((1 << BIN_SH) - 1)) << 17) | s;
      myrank[i] = atomicAdd(&lcnt[b], 1);
    } else {
      mybin[i] = -1;
    }
  }
  __syncthreads();
  // reserve one contiguous global segment per (block, bin)
  for (int i = t; i < nbins; i += 256)
    lbase[i] = lcnt[i] ? atomicAdd(&gcur[i], lcnt[i]) : 0;
  __syncthreads();
#pragma unroll
  for (int i = 0; i < KB_EPT; i++)
    if (mybin[i] >= 0) binbuf[lbase[mybin[i]] + myrank[i]] = myval[i];
}

// ---- kC: per-bin CSR build (one block per bin) ----
__global__ __launch_bounds__(256) void kC_build(
    const int* __restrict__ bin_base, const int* __restrict__ binbuf,
    int* __restrict__ col, int* __restrict__ rowptr, int* __restrict__ deg,
    float* __restrict__ in_norm, int n) {
  __shared__ int lcnt[256];
  __shared__ int lptr[256];
  int b = blockIdx.x;
  int t = threadIdx.x;
  int ebase = bin_base[b];
  int ecnt = bin_base[b + 1] - ebase;
  int node0 = b << BIN_SH;
  lcnt[t] = 0;
  __syncthreads();
  for (int i = t; i < ecnt; i += 256) {
    int v = binbuf[ebase + i];
    atomicAdd(&lcnt[v >> 17], 1);
  }
  __syncthreads();
  int cv = lcnt[t];
  lptr[t] = cv;
  __syncthreads();
#pragma unroll
  for (int off = 1; off < 256; off <<= 1) {
    int val = (t >= off) ? lptr[t - off] : 0;
    __syncthreads();
    lptr[t] += val;
    __syncthreads();
  }
  int ex = lptr[t] - cv;
  int node = node0 + t;
  if (node < n) {
    rowptr[node] = ebase + ex;
    deg[node] = cv;
    in_norm[node] = rsqrtf(fmaxf((float)cv, 1.0f));
  }
  __syncthreads();
  lptr[t] = ex;  // reuse as running cursor
  __syncthreads();
  for (int i = t; i < ecnt; i += 256) {
    int v = binbuf[ebase + i];
    int r = atomicAdd(&lptr[v >> 17], 1);
    col[ebase + r] = v & 0x1FFFF;  // block-local 16KB region -> L2 merges
  }
}

__device__ inline void acc8h(float* a, uint4 r, float nn) {
  const __half2* hp = reinterpret_cast<const __half2*>(&r);
#pragma unroll
  for (int i = 0; i < 4; i++) {
    float2 f = __half22float2(hp[i]);
    a[2 * i] += nn * f.x;
    a[2 * i + 1] += nn * f.y;
  }
}

// ---- pull64 + fused xw2: per wave gather/reduce -> LDS row -> block @W2 ----
__global__ __launch_bounds__(256) void pull64_xw2(
    const int* __restrict__ rowptr, const int* __restrict__ deg,
    const int* __restrict__ col, const __half* __restrict__ h1,
    const int* __restrict__ hist_s, const float* __restrict__ in_norm,
    const float* __restrict__ b1, const float* __restrict__ W2,
    __half* __restrict__ h2, int n) {
  __shared__ float W2s[64 * 32];
  __shared__ float xrow[4][64];
  int t = threadIdx.x;
#pragma unroll
  for (int i = 0; i < 8; i++) W2s[i * 256 + t] = W2[i * 256 + t];

  int w = t >> 6;
  int node = blockIdx.x * 4 + w;
  int l = t & 63;
  int sub = l >> 3, fq = l & 7;

  if (node < n) {
    int beg = rowptr[node];
    int end = beg + deg[node];
    float a0[8] = {0, 0, 0, 0, 0, 0, 0, 0};
    float a1[8] = {0, 0, 0, 0, 0, 0, 0, 0};
    int j = beg;
    for (; j + 16 <= end; j += 16) {
      int s0 = col[j + sub];
      int s1 = col[j + 8 + sub];
      float n0 = rsqrtf(fmaxf((float)hist_s[s0], 1.0f));
      float n1 = rsqrtf(fmaxf((float)hist_s[s1], 1.0f));
      uint4 r0 = ((const uint4*)h1)[(size_t)s0 * 8 + fq];
      uint4 r1 = ((const uint4*)h1)[(size_t)s1 * 8 + fq];
      acc8h(a0, r0, n0);
      acc8h(a1, r1, n1);
    }
    for (; j < end; j += 8) {
      int jj = j + sub;
      if (jj < end) {
        int s = col[jj];
        float nn = rsqrtf(fmaxf((float)hist_s[s], 1.0f));
        uint4 r = ((const uint4*)h1)[(size_t)s * 8 + fq];
        acc8h(a0, r, nn);
      }
    }
    float acc[8];
#pragma unroll
    for (int i = 0; i < 8; i++) acc[i] = a0[i] + a1[i];
#pragma unroll
    for (int d = 8; d <= 32; d <<= 1) {
#pragma unroll
      for (int i = 0; i < 8; i++) acc[i] += __shfl_xor(acc[i], d);
    }
    if (sub == 0) {
      float innv = in_norm[node];
      float onnv = rsqrtf(fmaxf((float)hist_s[node], 1.0f));
      float4 ba = ((const float4*)b1)[fq * 2];
      float4 bb = ((const float4*)b1)[fq * 2 + 1];
      float bv[8] = {ba.x, ba.y, ba.z, ba.w, bb.x, bb.y, bb.z, bb.w};
#pragma unroll
      for (int i = 0; i < 8; i++)
        xrow[w][fq * 8 + i] = fmaxf(acc[i] * innv + bv[i], 0.0f) * onnv;
    }
  }
  __syncthreads();
  if (t < 128) {
    int w2 = t >> 5, c = t & 31;
    int nd = blockIdx.x * 4 + w2;
    if (nd < n) {
      float dot = 0.f;
#pragma unroll 16
      for (int k = 0; k < 64; k++) dot += xrow[w2][k] * W2s[k * 32 + c];
      h2[(size_t)nd * 32 + c] = __float2half(dot);
    }
  }
}

// ---- pull 32 feats + epilogue: out = agg*in_norm + b2 ----
__global__ __launch_bounds__(256) void gcn_pull32(const int* __restrict__ rowptr,
                                                  const int* __restrict__ deg,
                                                  const int* __restrict__ col,
                                                  const __half* __restrict__ h,
                                                  const float* __restrict__ in_norm,
                                                  const float* __restrict__ b2,
                                                  float* __restrict__ out, int n) {
  int t = threadIdx.x;
  int node = blockIdx.x * 4 + (t >> 6);
  if (node >= n) return;
  int l = t & 63;
  int sub = l >> 3, fq = l & 7;
  int beg = rowptr[node];
  int end = beg + deg[node];
  float a0[4] = {0, 0, 0, 0}, a1[4] = {0, 0, 0, 0};
  int j = beg;
  for (; j + 16 <= end; j += 16) {
    int s0 = col[j + sub];
    int s1 = col[j + 8 + sub];
    uint2 r0 = ((const uint2*)h)[(size_t)s0 * 8 + fq];
    uint2 r1 = ((const uint2*)h)[(size_t)s1 * 8 + fq];
    const __half2* p0 = reinterpret_cast<const __half2*>(&r0);
    const __half2* p1 = reinterpret_cast<const __half2*>(&r1);
#pragma unroll
    for (int i = 0; i < 2; i++) {
      float2 f0 = __half22float2(p0[i]);
      float2 f1 = __half22float2(p1[i]);
      a0[2 * i] += f0.x; a0[2 * i + 1] += f0.y;
      a1[2 * i] += f1.x; a1[2 * i + 1] += f1.y;
    }
  }
  for (; j < end; j += 8) {
    int jj = j + sub;
    if (jj < end) {
      int s = col[jj];
      uint2 r = ((const uint2*)h)[(size_t)s * 8 + fq];
      const __half2* p = reinterpret_cast<const __half2*>(&r);
#pragma unroll
      for (int i = 0; i < 2; i++) {
        float2 f = __half22float2(p[i]);
        a0[2 * i] += f.x; a0[2 * i + 1] += f.y;
      }
    }
  }
  float acc[4];
#pragma unroll
  for (int i = 0; i < 4; i++) acc[i] = a0[i] + a1[i];
#pragma unroll
  for (int d = 8; d <= 32; d <<= 1) {
#pragma unroll
    for (int i = 0; i < 4; i++) acc[i] += __shfl_xor(acc[i], d);
  }
  if (sub == 0) {
    float s = in_norm[node];
    float4 bb = ((const float4*)b2)[fq];
    float4 o;
    o.x = acc[0] * s + bb.x;
    o.y = acc[1] * s + bb.y;
    o.z = acc[2] * s + bb.z;
    o.w = acc[3] * s + bb.w;
    ((float4*)out)[(size_t)node * 8 + fq] = o;
  }
}

extern "C" void kernel_launch(void* const* d_in, const int* in_sizes, int n_in,
                              void* d_out, int out_size, void* d_ws, size_t ws_size,
                              hipStream_t stream) {
  const float* x   = (const float*)d_in[0];
  const int*   src = (const int*)d_in[1];
  const int*   dst = (const int*)d_in[2];
  const float* W1  = (const float*)d_in[3];
  const float* b1  = (const float*)d_in[4];
  const float* W2  = (const float*)d_in[5];
  const float* b2  = (const float*)d_in[6];
  float* out = (float*)d_out;

  const int N = in_sizes[0] / 64;   // 100000
  const int E = in_sizes[1];        // 1600000
  const int NBINS = (N + (1 << BIN_SH) - 1) >> BIN_SH;  // 391

  int* hist_s   = (int*)d_ws;                  // N
  int* deg      = hist_s + N;                  // N
  int* rowptr   = deg + N;                     // N
  int* bin_cnt  = rowptr + N;                  // 512
  int* bin_base = bin_cnt + 512;               // 516 (padded for h1 alignment)
  int* gcur     = bin_base + 516;              // 512
  int* binbuf   = gcur + 512;                  // E
  int* col      = binbuf + E;                  // E
  float* in_norm = (float*)(col + E);          // N
  __half* h1 = (__half*)(in_norm + N);         // 64N halves (16B aligned)
  __half* h2 = h1 + (size_t)64 * N;            // 32N halves

  hipMemsetAsync(hist_s, 0, (size_t)N * sizeof(int), stream);
  hipMemsetAsync(bin_cnt, 0, 512 * sizeof(int), stream);

  const int HB = 512;                      // hist blocks
  const int EPB = (E + HB - 1) / HB;       // 3125 edges per hist block
  const int GX = (N + 15) / 16;            // 6250 xw1 blocks
  k1_hist_xw1<<<HB + GX, 256, 0, stream>>>(src, dst, hist_s, bin_cnt, x, W1, h1,
                                           E, N, HB, GX, EPB, NBINS);
  scan_bins<<<1, 512, 0, stream>>>(bin_cnt, bin_base, gcur, NBINS);
  kB_binscatter<<<(E + 256 * KB_EPT - 1) / (256 * KB_EPT), 256, 0, stream>>>(
      src, dst, gcur, binbuf, E, NBINS);
  kC_build<<<NBINS, 256, 0, stream>>>(bin_base, binbuf, col, rowptr, deg, in_norm, N);
  pull64_xw2<<<(N + 3) / 4, 256, 0, stream>>>(rowptr, deg, col, h1, hist_s,
                                              in_norm, b1, W2, h2, N);
  gcn_pull32<<<(N + 3) / 4, 256, 0, stream>>>(rowptr, deg, col, h2, in_norm, b2, out, N);
}